// Round 4
// baseline (1108.540 us; speedup 1.0000x reference)
//
#include <hip/hip_runtime.h>

#define B_SZ  32768
#define S_MC  4
#define D_IN  256
#define LAT   8
#define NBINS 300
#define KDIM  1323
#define RNK   4

typedef float f32x4 __attribute__((ext_vector_type(4)));

constexpr int TPB   = 256;
constexpr int BPB   = 4;                 // batch rows per block
constexpr int NPASS = S_MC + 1;          // 4 samples + mean path
constexpr int NF4   = 330;               // aligned float4 groups per row
constexpr int ITER1 = NF4 - TPB;         // 74 threads own a 2nd group

// Row stride is 5292 B = 12 (mod 16). Picking k == b (mod 4) makes
// &out[row_base + k] 16B-aligned: 12*b + 4*(b&3 + 4j) == 16*b == 0 (mod 16).

__global__ __launch_bounds__(TPB) void cp_profile_kernel(
    const float* __restrict__ x,       // (B, 256)
    const float* __restrict__ eps,     // (S, B, 8)
    const float* __restrict__ A,       // (300, 4)
    const float* __restrict__ Bm,      // (1323, 4)
    const float* __restrict__ C,       // (8, 4)
    const float* __restrict__ bias,    // (300, 1323)
    const float* __restrict__ mu_w,    // (8, 256)
    const float* __restrict__ mu_b,    // (8,)
    const float* __restrict__ std_w,   // (8, 256)
    const float* __restrict__ std_b,   // (8,)
    const int*   __restrict__ glab,    // (B,)
    float* __restrict__ out)
{
    __shared__ float muh_s[LAT];
    __shared__ float stdh_s[LAT];
    __shared__ float w_s[NPASS][RNK];
    __shared__ float redmax_s[4][NPASS];
    __shared__ float redsum_s[4][NPASS];

    const int tid  = threadIdx.x;
    const int lane = tid & 63;
    const int wid  = tid >> 6;
    const f32x4* B4 = reinterpret_cast<const f32x4*>(Bm);

    for (int bb = 0; bb < BPB; ++bb) {
        const int b = blockIdx.x * BPB + bb;
        const int g = glab[b];
        const int p = b & 3;             // alignment phase for this row

        // ---- 16 dot products (8 mu, 8 std pre-acts), 4 per wave ----
        const f32x4* x4 = reinterpret_cast<const f32x4*>(x + (size_t)b * D_IN);
        const f32x4 xv = x4[lane];
        float dotv[4];
        #pragma unroll
        for (int dd = 0; dd < 4; ++dd) {
            const int d = wid * 4 + dd;
            const f32x4* W4 = reinterpret_cast<const f32x4*>(
                (d < LAT) ? (mu_w + d * D_IN) : (std_w + (d - LAT) * D_IN));
            const f32x4 wv = W4[lane];
            float a = xv.x * wv.x + xv.y * wv.y + xv.z * wv.z + xv.w * wv.w;
            #pragma unroll
            for (int off = 32; off > 0; off >>= 1)
                a += __shfl_xor(a, off, 64);
            dotv[dd] = a;
        }
        if (lane == 0) {
            #pragma unroll
            for (int dd = 0; dd < 4; ++dd) {
                const int d = wid * 4 + dd;
                if (d < LAT) {
                    muh_s[d] = dotv[dd] + mu_b[d];
                } else {
                    const float y = dotv[dd] + std_b[d - LAT];
                    stdh_s[d - LAT] = fmaxf(y, 0.f) + log1pf(expf(-fabsf(y)));
                }
            }
        }
        __syncthreads();

        // ---- CP weights w[s][r] = A_n[r] * z[s][r]; s==4 is the mean path ----
        if (tid < 20) {
            const int s = tid >> 2, r = tid & 3;
            const float* ep = eps + ((size_t)(s < S_MC ? s : 0) * B_SZ + b) * LAT;
            float z = 0.f;
            #pragma unroll
            for (int j = 0; j < LAT; ++j) {
                float h = muh_s[j];
                if (s < S_MC) h += stdh_s[j] * ep[j];
                z += h * C[j * RNK + r];
            }
            w_s[s][r] = A[g * RNK + r] * z;
        }
        // small outputs (mu_h / std_h, fp32)
        const size_t base_small = (size_t)NPASS * B_SZ * KDIM;
        if (tid >= 32 && tid < 40)
            out[base_small + (size_t)b * LAT + (tid - 32)] = muh_s[tid - 32];
        if (tid >= 40 && tid < 48)
            out[base_small + (size_t)B_SZ * LAT + (size_t)b * LAT + (tid - 40)] = stdh_s[tid - 40];
        __syncthreads();

        float wr[NPASS][RNK];
        #pragma unroll
        for (int s = 0; s < NPASS; ++s)
            #pragma unroll
            for (int r = 0; r < RNK; ++r)
                wr[s][r] = w_s[s][r];

        // ---- per-thread k ownership: f4 group(s) + 3 leftover scalars ----
        const int  k0 = p + 4 * tid;                 // always valid (tid<256<=329)
        const bool v1 = (tid < ITER1);
        const int  k1 = p + 4 * (TPB + tid);
        const int  e  = tid - 100;
        const bool vht = (e >= 0 && e < 3);
        const int  kht = vht ? ((e < p) ? e : (1320 + e)) : 0;

        const float* biasg = bias + (size_t)g * KDIM;
        f32x4 br0[4], br1[4];
        float bv0[4], bv1[4];
        #pragma unroll
        for (int q = 0; q < 4; ++q) {
            br0[q] = B4[k0 + q];
            bv0[q] = biasg[k0 + q];
            if (v1) { br1[q] = B4[k1 + q]; bv1[q] = biasg[k1 + q]; }
            else    { br1[q] = (f32x4)(0.f); bv1[q] = -INFINITY; }
        }
        f32x4 brht = (f32x4)(0.f);
        float bvht = -INFINITY;
        if (vht) { brht = B4[kht]; bvht = biasg[kht]; }

        auto LG = [&](const f32x4& r4, float bi, int s) -> float {
            return fmaf(wr[s][0], r4.x,
                   fmaf(wr[s][1], r4.y,
                   fmaf(wr[s][2], r4.z, wr[s][3] * r4.w))) + bi;
        };

        // ---- sweep 1: running max (invalid slots contribute -inf) ----
        float lmax[NPASS];
        #pragma unroll
        for (int s = 0; s < NPASS; ++s) {
            float m0 = -INFINITY;
            #pragma unroll
            for (int q = 0; q < 4; ++q) {
                m0 = fmaxf(m0, LG(br0[q], bv0[q], s));
                m0 = fmaxf(m0, LG(br1[q], bv1[q], s));
            }
            lmax[s] = fmaxf(m0, LG(brht, bvht, s));
        }
        #pragma unroll
        for (int s = 0; s < NPASS; ++s)
            #pragma unroll
            for (int off = 32; off > 0; off >>= 1)
                lmax[s] = fmaxf(lmax[s], __shfl_xor(lmax[s], off, 64));
        if (lane == 0) {
            #pragma unroll
            for (int s = 0; s < NPASS; ++s) redmax_s[wid][s] = lmax[s];
        }
        __syncthreads();

        float m[NPASS];
        #pragma unroll
        for (int s = 0; s < NPASS; ++s)
            m[s] = fmaxf(fmaxf(redmax_s[0][s], redmax_s[1][s]),
                         fmaxf(redmax_s[2][s], redmax_s[3][s]));

        // ---- sweep 2: recompute -> exp -> running sum (exp(-inf)=0) ----
        float lsum[NPASS];
        #pragma unroll
        for (int s = 0; s < NPASS; ++s) {
            float a = 0.f;
            #pragma unroll
            for (int q = 0; q < 4; ++q) {
                a += __expf(LG(br0[q], bv0[q], s) - m[s]);
                a += __expf(LG(br1[q], bv1[q], s) - m[s]);
            }
            lsum[s] = a + __expf(LG(brht, bvht, s) - m[s]);
        }
        #pragma unroll
        for (int s = 0; s < NPASS; ++s)
            #pragma unroll
            for (int off = 32; off > 0; off >>= 1)
                lsum[s] += __shfl_xor(lsum[s], off, 64);
        if (lane == 0) {
            #pragma unroll
            for (int s = 0; s < NPASS; ++s) redsum_s[wid][s] = lsum[s];
        }
        __syncthreads();

        float inv[NPASS];
        #pragma unroll
        for (int s = 0; s < NPASS; ++s)
            inv[s] = 1.f / (redsum_s[0][s] + redsum_s[1][s] +
                            redsum_s[2][s] + redsum_s[3][s]);

        // ---- sweep 3: recompute -> exp -> normalize -> ALIGNED f4 nt stores ----
        #pragma unroll
        for (int s = 0; s < NPASS; ++s) {
            const size_t ob = (s < S_MC)
                ? ((size_t)((size_t)s * B_SZ + b) * KDIM)
                : ((size_t)S_MC * B_SZ * KDIM + (size_t)b * KDIM);
            f32x4 o0;
            o0.x = __expf(LG(br0[0], bv0[0], s) - m[s]) * inv[s];
            o0.y = __expf(LG(br0[1], bv0[1], s) - m[s]) * inv[s];
            o0.z = __expf(LG(br0[2], bv0[2], s) - m[s]) * inv[s];
            o0.w = __expf(LG(br0[3], bv0[3], s) - m[s]) * inv[s];
            __builtin_nontemporal_store(
                o0, reinterpret_cast<f32x4*>(out + ob + k0));
            if (v1) {
                f32x4 o1;
                o1.x = __expf(LG(br1[0], bv1[0], s) - m[s]) * inv[s];
                o1.y = __expf(LG(br1[1], bv1[1], s) - m[s]) * inv[s];
                o1.z = __expf(LG(br1[2], bv1[2], s) - m[s]) * inv[s];
                o1.w = __expf(LG(br1[3], bv1[3], s) - m[s]) * inv[s];
                __builtin_nontemporal_store(
                    o1, reinterpret_cast<f32x4*>(out + ob + k1));
            }
            if (vht) {
                const float v = __expf(LG(brht, bvht, s) - m[s]) * inv[s];
                __builtin_nontemporal_store(v, out + ob + kht);
            }
        }
    }
}

extern "C" void kernel_launch(void* const* d_in, const int* in_sizes, int n_in,
                              void* d_out, int out_size, void* d_ws, size_t ws_size,
                              hipStream_t stream) {
    const float* x     = (const float*)d_in[0];
    const float* eps   = (const float*)d_in[1];
    const float* A     = (const float*)d_in[2];
    const float* Bm    = (const float*)d_in[3];
    const float* C     = (const float*)d_in[4];
    const float* bias  = (const float*)d_in[5];
    const float* mu_w  = (const float*)d_in[6];
    const float* mu_b  = (const float*)d_in[7];
    const float* std_w = (const float*)d_in[8];
    const float* std_b = (const float*)d_in[9];
    const int*   glab  = (const int*)d_in[10];
    float* out = (float*)d_out;

    cp_profile_kernel<<<B_SZ / BPB, TPB, 0, stream>>>(
        x, eps, A, Bm, C, bias, mu_w, mu_b, std_w, std_b, glab, out);
}